// Round 9
// baseline (93.422 us; speedup 1.0000x reference)
//
#include <hip/hip_runtime.h>
#include <hip/hip_bf16.h>

typedef __bf16 bf16_t;
typedef __bf16 bf16x8 __attribute__((ext_vector_type(8)));
typedef __bf16 bf16x4 __attribute__((ext_vector_type(4)));
typedef float  f32x4  __attribute__((ext_vector_type(4)));
typedef unsigned int u32x4 __attribute__((ext_vector_type(4)));

#define MFMA16(a,b,c) __builtin_amdgcn_mfma_f32_16x16x32_bf16(a,b,c,0,0,0)

constexpr int B_ = 2, T_ = 2048, H_ = 16, D_ = 64, C_ = 1024;
constexpr int GK = C_;          // GEMM K dim (1024)

// async global->LDS, 16B per lane. LDS dest: wave-uniform base + lane*16.
typedef const __attribute__((address_space(1))) unsigned char ga_t;
typedef __attribute__((address_space(3))) unsigned char la_t;
__device__ __forceinline__ void gld16(const void* g, void* l) {
  __builtin_amdgcn_global_load_lds((ga_t*)g, (la_t*)l, 16, 0, 0);
}

// ---------------- cast fp32 -> bf16 (X, Wq, Wk, Wv, Wp) ----------------
__global__ __launch_bounds__(256) void cast_all(
    const float* __restrict__ X,  const float* __restrict__ Wq,
    const float* __restrict__ Wk, const float* __restrict__ Wv,
    const float* __restrict__ Wp,
    bf16_t* __restrict__ Xb,  bf16_t* __restrict__ Wqb, bf16_t* __restrict__ Wkb,
    bf16_t* __restrict__ Wvb, bf16_t* __restrict__ Wpb)
{
  int i = blockIdx.x * 256 + threadIdx.x;   // each thread converts 4 floats
  const float* src; bf16_t* dst; int off;
  if      (i < 1048576) { src = X;  dst = Xb;  off = i; }
  else if (i < 1310720) { src = Wq; dst = Wqb; off = i - 1048576; }
  else if (i < 1572864) { src = Wk; dst = Wkb; off = i - 1310720; }
  else if (i < 1835008) { src = Wv; dst = Wvb; off = i - 1572864; }
  else                  { src = Wp; dst = Wpb; off = i - 1835008; }
  float4 v = *reinterpret_cast<const float4*>(src + (size_t)off * 4);
  bf16x4 o;
  o[0] = (bf16_t)v.x; o[1] = (bf16_t)v.y; o[2] = (bf16_t)v.z; o[3] = (bf16_t)v.w;
  *reinterpret_cast<bf16x4*>(dst + (size_t)off * 4) = o;
}

// =============================================================================
// Shared 128x128 BK=64 counted-vmcnt GEMM core (kept for gemm_proj).
// =============================================================================
__device__ __forceinline__ void gemm128_core(
    const bf16_t* __restrict__ A, const bf16_t* __restrict__ Bw,
    bf16_t* sA, bf16_t* sB, f32x4 (&acc)[4][2], int bx, int by)
{
  const int tid = threadIdx.x, lane = tid & 63, wid = tid >> 6;
  const int wm = wid >> 2, wn = wid & 3;
  const int g = lane >> 4, c = lane & 15, rk = c & 7;
  const int srow = tid >> 3;                    // 0..63 rows per 64-row slab
  const int sg   = (tid & 7) ^ (srow & 7);      // pre-swizzled source granule
  const bf16_t* asrc = A  + (size_t)(bx * 128 + srow) * GK + sg * 8;
  const bf16_t* bsrc = Bw + (size_t)(by * 128 + srow) * GK + sg * 8;

  #define STGP(buf, kt)                                                       \
    { char* da = (char*)sA + (buf) * 16384;                                   \
      char* db = (char*)sB + (buf) * 16384;                                   \
      _Pragma("unroll")                                                       \
      for (int it = 0; it < 2; ++it) {                                        \
        gld16(asrc + (size_t)it * 65536 + (kt) * 64, da + (it * 512 + tid) * 16); \
        gld16(bsrc + (size_t)it * 65536 + (kt) * 64, db + (it * 512 + tid) * 16); \
      } }

  #define ITERP(t, buf)                                                       \
    {                                                                         \
      if ((t) < 15) asm volatile("s_waitcnt vmcnt(4)");                       \
      else          asm volatile("s_waitcnt vmcnt(0)");                       \
      __builtin_amdgcn_s_barrier();                                           \
      __builtin_amdgcn_sched_barrier(0);                                      \
      const char* ca = (const char*)sA + (buf) * 16384;                       \
      const char* cb = (const char*)sB + (buf) * 16384;                       \
      bf16x8 af[4][2], bfr[2][2];                                             \
      _Pragma("unroll")                                                       \
      for (int mi = 0; mi < 4; ++mi)                                          \
        _Pragma("unroll")                                                     \
        for (int ks = 0; ks < 2; ++ks)                                        \
          af[mi][ks] = *reinterpret_cast<const bf16x8*>(                      \
              ca + (wm * 64 + mi * 16 + c) * 128 + (((ks * 4 + g) ^ rk) * 16)); \
      _Pragma("unroll")                                                       \
      for (int ni = 0; ni < 2; ++ni)                                          \
        _Pragma("unroll")                                                     \
        for (int ks = 0; ks < 2; ++ks)                                        \
          bfr[ni][ks] = *reinterpret_cast<const bf16x8*>(                     \
              cb + (wn * 32 + ni * 16 + c) * 128 + (((ks * 4 + g) ^ rk) * 16)); \
      asm volatile("s_waitcnt lgkmcnt(0)");                                   \
      __builtin_amdgcn_sched_barrier(0);                                      \
      __builtin_amdgcn_s_barrier();                                           \
      __builtin_amdgcn_sched_barrier(0);                                      \
      if ((t) + 2 < 16) STGP(buf, (t) + 2);                                   \
      __builtin_amdgcn_s_setprio(1);                                          \
      _Pragma("unroll")                                                       \
      for (int ks = 0; ks < 2; ++ks)                                          \
        _Pragma("unroll")                                                     \
        for (int mi = 0; mi < 4; ++mi)                                        \
          _Pragma("unroll")                                                   \
          for (int ni = 0; ni < 2; ++ni)                                      \
            acc[mi][ni] = MFMA16(af[mi][ks], bfr[ni][ks], acc[mi][ni]);       \
      __builtin_amdgcn_s_setprio(0);                                          \
    }

  STGP(0, 0);                                   // prologue: 2 tiles in flight
  STGP(1, 1);
  #pragma unroll 1
  for (int t0 = 0; t0 < 16; t0 += 2) {
    ITERP(t0, 0);
    ITERP(t0 + 1, 1);
  }
  #undef ITERP
  #undef STGP
}

// ---------------- fused QKV projection: C[4096,3072] = Xb @ Wqkv^T -----------
// 256x256 tile, BK=64, 8 waves (2M x 4N), wave-tile 128x64 -> acc[8][4].
// Register-subtiled 4-phase K-tile: 64 MFMA per wave per barrier-pair (vs 16 in
// the 2-phase core — the T3 regime escape). Counted vmcnt(8) keeps next tile's
// loads in flight; stage(t+2) runs under the 4th MFMA phase. LDS 128KB, 1
// blk/CU (in-block phase overlap replaces cross-block overlap, m201 regime).
// Grid 16x12 = 192 blocks. mode = by>>2 block-uniform.
__global__ __launch_bounds__(512, 2) void gemm_qkv(
    const bf16_t* __restrict__ Xb, const bf16_t* __restrict__ Wqkv,
    bf16_t* __restrict__ qo, bf16_t* __restrict__ ko, bf16_t* __restrict__ vto)
{
  __shared__ bf16_t sA[2][256 * 64];            // 64 KB
  __shared__ bf16_t sB[2][256 * 64];            // 64 KB
  const int tid = threadIdx.x, lane = tid & 63, wid = tid >> 6;
  const int wm = wid >> 2, wn = wid & 3;        // 2 x 4 wave grid
  const int g = lane >> 4, c = lane & 15, rk = c & 7;
  const int bx = blockIdx.x, by = blockIdx.y;
  const int srow = tid >> 3;                    // 0..63 rows per 64-row slab
  const int sg   = (tid & 7) ^ (srow & 7);      // pre-swizzled source granule
  const bf16_t* asrc = Xb   + (size_t)(bx * 256 + srow) * GK + sg * 8;
  const bf16_t* bsrc = Wqkv + (size_t)(by * 256 + srow) * GK + sg * 8;
  f32x4 acc[8][4] = {};                         // 128 VGPRs

  // stage K-tile kt into buffer buf: 4 A-slabs + 4 B-slabs, 8 gld16/thread
  #define STG(buf, kt)                                                        \
    { char* da = (char*)sA + (buf) * 32768;                                   \
      char* db = (char*)sB + (buf) * 32768;                                   \
      _Pragma("unroll")                                                       \
      for (int it = 0; it < 4; ++it)                                          \
        gld16(asrc + (size_t)it * 65536 + (kt) * 64, da + (it * 512 + tid) * 16); \
      _Pragma("unroll")                                                       \
      for (int it = 0; it < 4; ++it)                                          \
        gld16(bsrc + (size_t)it * 65536 + (kt) * 64, db + (it * 512 + tid) * 16); \
    }

  #define RD_A(dst, mi)                                                       \
    _Pragma("unroll")                                                         \
    for (int ks = 0; ks < 2; ++ks)                                            \
      dst[ks] = *reinterpret_cast<const bf16x8*>(                             \
          ca + (wm * 128 + (mi) * 16 + c) * 128 + (((ks * 4 + g) ^ rk) * 16));
  #define RD_B(dst, ni)                                                       \
    _Pragma("unroll")                                                         \
    for (int ks = 0; ks < 2; ++ks)                                            \
      dst[ks] = *reinterpret_cast<const bf16x8*>(                             \
          cb + (wn * 64 + (ni) * 16 + c) * 128 + (((ks * 4 + g) ^ rk) * 16));
  #define MM16(ah, nlo, accrow)                                               \
    __builtin_amdgcn_s_setprio(1);                                            \
    _Pragma("unroll")                                                         \
    for (int ks = 0; ks < 2; ++ks)                                            \
      _Pragma("unroll")                                                       \
      for (int i = 0; i < 4; ++i)                                             \
        _Pragma("unroll")                                                     \
        for (int n = 0; n < 2; ++n)                                           \
          acc[(accrow) + i][(nlo) + n] =                                      \
              MFMA16(ah[i][ks], bfr[(nlo) + n][ks], acc[(accrow) + i][(nlo) + n]); \
    __builtin_amdgcn_s_setprio(0);

  STG(0, 0);                                    // prologue: 2 tiles in flight
  STG(1, 1);
  #pragma unroll 1
  for (int t = 0; t < 16; ++t) {
    const int cur = t & 1;
    if (t < 15) asm volatile("s_waitcnt vmcnt(8)");   // tile t landed; t+1 in flight
    else        asm volatile("s_waitcnt vmcnt(0)");
    __builtin_amdgcn_s_barrier();
    __builtin_amdgcn_sched_barrier(0);
    const char* ca = (const char*)sA + cur * 32768;
    const char* cb = (const char*)sB + cur * 32768;

    bf16x8 afr[4][2], bfr[4][2];
    // P1: A-half0 (mi 0-3) + B ni 0-1 -> quad (0-3, 0-1)
    #pragma unroll
    for (int i = 0; i < 4; ++i) { RD_A(afr[i], i) }
    #pragma unroll
    for (int n = 0; n < 2; ++n) { RD_B(bfr[n], n) }
    asm volatile("s_waitcnt lgkmcnt(0)");
    __builtin_amdgcn_sched_barrier(0);
    MM16(afr, 0, 0)
    // P2: B ni 2-3 -> quad (0-3, 2-3)
    #pragma unroll
    for (int n = 2; n < 4; ++n) { RD_B(bfr[n], n) }
    asm volatile("s_waitcnt lgkmcnt(0)");
    __builtin_amdgcn_sched_barrier(0);
    MM16(afr, 2, 0)
    // P3: A-half1 (mi 4-7, reuse regs) -> quad (4-7, 2-3)
    #pragma unroll
    for (int i = 0; i < 4; ++i) { RD_A(afr[i], 4 + i) }
    asm volatile("s_waitcnt lgkmcnt(0)");
    __builtin_amdgcn_sched_barrier(0);
    MM16(afr, 2, 4)
    // all my reads of buf[cur] are done -> free it for staging
    __builtin_amdgcn_s_barrier();
    __builtin_amdgcn_sched_barrier(0);
    if (t + 2 < 16) STG(cur, t + 2);            // refill under P4's MFMAs
    // P4: quad (4-7, 0-1) — afr(half1) + bfr(0-1) still live in regs
    MM16(afr, 0, 4)
  }
  #undef MM16
  #undef RD_B
  #undef RD_A
  #undef STG

  // epilogue: scatter to q / k / v^T. mode uniform per block (by>>2).
  const float qscale = 0.04508422002778f;       // log2(e) * 1024^-0.5
  const int mode = by >> 2;                     // 0=q, 1=k, 2=v
  #pragma unroll
  for (int ni = 0; ni < 4; ++ni) {
    int col = by * 256 + wn * 64 + ni * 16 + c;
    int cm  = col & 1023;
    int h = cm >> 6, d = cm & 63;
    #pragma unroll
    for (int mi = 0; mi < 8; ++mi) {
      int row0 = bx * 256 + wm * 128 + mi * 16 + g * 4;
      int b = row0 >> 11, tt0 = row0 & 2047;
      if (mode == 2) {                          // v: [b,h,d,t] -> t contiguous
        bf16x4 wv;
        #pragma unroll
        for (int r = 0; r < 4; ++r) wv[r] = (bf16_t)acc[mi][ni][r];
        *reinterpret_cast<bf16x4*>(
            &vto[((size_t)(b * H_ + h) * D_ + d) * T_ + tt0]) = wv;
      } else {
        bf16_t* dst = (mode == 0) ? qo : ko;
        float   sc  = (mode == 0) ? qscale : 1.0f;
        #pragma unroll
        for (int r = 0; r < 4; ++r)
          dst[((size_t)(b * H_ + h) * T_ + (tt0 + r)) * D_ + d] =
              (bf16_t)(acc[mi][ni][r] * sc);
      }
    }
  }
}

// ---------------- flash attention (causal) -----------------------------------
// v4 (reverted from the R8 j-split regression): 4-wave blocks, counted-vmcnt
// K/V pipeline, fixed-m softmax (m=8 folded into QK C-in; exp2 domain; 2^-8
// cancels in O=PV/l), in-register P^T->B-frag via cvt_pk + permlane swaps.
__global__ __launch_bounds__(256, 4) void attn_fwd(
    const bf16_t* __restrict__ q, const bf16_t* __restrict__ k,
    const bf16_t* __restrict__ vt, bf16_t* __restrict__ att)
{
  __shared__ bf16_t sK[2][64 * 64], sV[2][64 * 64];   // 16KB + 16KB
  const int tid = threadIdx.x, lane = tid & 63, w = tid >> 6;
  const int g = lane >> 4, c = lane & 15;
  const int bid = blockIdx.x;
  const int qt = 31 - (bid >> 5);                     // longest blocks first
  const int bh = bid & 31;
  const bf16_t* qb = q  + (size_t)bh * T_ * D_;
  const bf16_t* kb = k  + (size_t)bh * T_ * D_;
  const bf16_t* vb = vt + (size_t)bh * D_ * T_;       // vt[d][t]

  // Q fragments straight from global (read once)
  bf16x8 qa[2];
  #pragma unroll
  for (int ks = 0; ks < 2; ++ks)
    qa[ks] = *reinterpret_cast<const bf16x8*>(
        qb + (size_t)(qt * 64 + w * 16 + c) * D_ + ks * 32 + g * 8);

  // stage tile kt into buffer buf: 2 K-loads + 2 V-loads per thread (4 gld16)
  const int srow = tid >> 3, sgr0 = tid & 7;
  #define STAGE(buf, kt)                                                        \
    {                                                                           \
      char* kdst = (char*)sK + (size_t)(buf) * 8192;                            \
      char* vdst = (char*)sV + (size_t)(buf) * 8192;                            \
      _Pragma("unroll")                                                         \
      for (int it = 0; it < 2; ++it) {                                          \
        int idx = it * 256 + tid;                                               \
        int row = it * 32 + srow;                                               \
        int sg  = sgr0 ^ (row & 7);                                             \
        gld16(kb + (size_t)((kt) * 64 + row) * D_ + sg * 8, kdst + idx * 16);   \
        gld16(vb + (size_t)row * T_ + (kt) * 64 + sg * 8,   vdst + idx * 16);   \
      }                                                                         \
    }

  STAGE(0, 0);                                        // prologue: 2 in flight
  if (qt >= 1) STAGE(1, 1);

  float l_r = 0.f;                                    // per-lane l (q = c)
  f32x4 acc_t[4] = {};                                // O^T frags [d-block]
  const int rowK = c & 7;                             // swizzle key per lane

  #pragma unroll 1
  for (int kt = 0; kt <= qt; ++kt) {
    const int cur = kt & 1;
    if (kt < qt) asm volatile("s_waitcnt vmcnt(4)");
    else         asm volatile("s_waitcnt vmcnt(0)");
    __builtin_amdgcn_s_barrier();
    __builtin_amdgcn_sched_barrier(0);

    const char* kc = (char*)sK + (size_t)cur * 8192;
    const char* vc = (char*)sV + (size_t)cur * 8192;
    bf16x8 kf[2][4], vf[2][4];
    #pragma unroll
    for (int ks = 0; ks < 2; ++ks)
      #pragma unroll
      for (int f = 0; f < 4; ++f) {
        int rb = (f * 16 + c) * 128;
        int gsw = ((ks * 4 + g) ^ rowK) * 16;
        kf[ks][f] = *reinterpret_cast<const bf16x8*>(kc + rb + gsw);
        vf[ks][f] = *reinterpret_cast<const bf16x8*>(vc + rb + gsw);
      }
    asm volatile("s_waitcnt lgkmcnt(0)");             // my reads of buf done
    __builtin_amdgcn_sched_barrier(0);
    __builtin_amdgcn_s_barrier();                     // all waves' reads done
    __builtin_amdgcn_sched_barrier(0);
    if (kt + 2 <= qt) STAGE(cur, kt + 2);             // refill freed buffer

    // S^T - 8 = K Q^T + (-8): fixed-m softmax, m=8 folded into C-in
    f32x4 s[4];
    #pragma unroll
    for (int fj = 0; fj < 4; ++fj) {
      s[fj][0] = -8.f; s[fj][1] = -8.f; s[fj][2] = -8.f; s[fj][3] = -8.f;
    }
    __builtin_amdgcn_s_setprio(1);
    #pragma unroll
    for (int fj = 0; fj < 4; ++fj)
      #pragma unroll
      for (int ks = 0; ks < 2; ++ks)
        s[fj] = MFMA16(kf[ks][fj], qa[ks], s[fj]);
    __builtin_amdgcn_s_setprio(0);

    if (kt == qt) {                                   // causal mask on diagonal
      #pragma unroll
      for (int fj = 0; fj < 4; ++fj)
        #pragma unroll
        for (int r = 0; r < 4; ++r)
          if (fj * 16 + g * 4 + r > w * 16 + c) s[fj][r] = -1e30f;
    }

    // P = exp2(s); pack to bf16 pairs; tree-summed l (1 dependent add)
    unsigned pk[4][2];
    float ls[4];
    #pragma unroll
    for (int fj = 0; fj < 4; ++fj) {
      float pe0 = __builtin_amdgcn_exp2f(s[fj][0]);
      float pe1 = __builtin_amdgcn_exp2f(s[fj][1]);
      float pe2 = __builtin_amdgcn_exp2f(s[fj][2]);
      float pe3 = __builtin_amdgcn_exp2f(s[fj][3]);
      ls[fj] = (pe0 + pe1) + (pe2 + pe3);
      asm("v_cvt_pk_bf16_f32 %0, %1, %2" : "=v"(pk[fj][0]) : "v"(pe0), "v"(pe1));
      asm("v_cvt_pk_bf16_f32 %0, %1, %2" : "=v"(pk[fj][1]) : "v"(pe2), "v"(pe3));
    }
    l_r += (ls[0] + ls[1]) + (ls[2] + ls[3]);

    // in-register P^T -> B-frag redistribution (replaces sP LDS round-trip)
    bf16x8 pf[2];
    #pragma unroll
    for (int ks = 0; ks < 2; ++ks) {
      unsigned x0 = pk[2 * ks][0], y0 = pk[2 * ks + 1][0];
      unsigned x1 = pk[2 * ks][1], y1 = pk[2 * ks + 1][1];
      asm("v_permlane32_swap_b32 %0, %1" : "+v"(x0), "+v"(y0));
      asm("v_permlane32_swap_b32 %0, %1" : "+v"(x1), "+v"(y1));
      asm("v_permlane16_swap_b32 %0, %1" : "+v"(x0), "+v"(y0));
      asm("v_permlane16_swap_b32 %0, %1" : "+v"(x1), "+v"(y1));
      u32x4 t; t[0] = x0; t[1] = x1; t[2] = y0; t[3] = y1;
      pf[ks] = __builtin_bit_cast(bf16x8, t);
    }

    // O^T += V^T P^T
    __builtin_amdgcn_s_setprio(1);
    #pragma unroll
    for (int fd = 0; fd < 4; ++fd)
      #pragma unroll
      for (int ks = 0; ks < 2; ++ks)
        acc_t[fd] = MFMA16(vf[ks][fd], pf[ks], acc_t[fd]);
    __builtin_amdgcn_s_setprio(0);
  }

  // deferred l reduce across the 4 g-groups, then write O
  l_r += __shfl_xor(l_r, 16);
  l_r += __shfl_xor(l_r, 32);
  float inv = 1.0f / l_r;
  const int b = bh >> 4, h = bh & 15;
  const int t = qt * 64 + w * 16 + c;
  #pragma unroll
  for (int fd = 0; fd < 4; ++fd) {
    bf16x4 wv;
    #pragma unroll
    for (int r = 0; r < 4; ++r) wv[r] = (bf16_t)(acc_t[fd][r] * inv);
    int d = fd * 16 + g * 4;
    *reinterpret_cast<bf16x4*>(&att[((size_t)(b * T_ + t) * H_ + h) * D_ + d]) = wv;
  }
  #undef STAGE
}

// ---------------- output projection: out = att @ Wp^T + bp (fp32 out) --------
__global__ __launch_bounds__(512, 2) void gemm_proj(
    const bf16_t* __restrict__ attb, const bf16_t* __restrict__ Wpb,
    const float* __restrict__ bp, float* __restrict__ out)
{
  __shared__ bf16_t sA[2][128 * 64];            // 32 KB
  __shared__ bf16_t sB[2][128 * 64];            // 32 KB
  f32x4 acc[4][2] = {};
  const int bx = blockIdx.x, by = blockIdx.y;
  gemm128_core(attb, Wpb, &sA[0][0], &sB[0][0], acc, bx, by);

  const int tid = threadIdx.x, lane = tid & 63, wid = tid >> 6;
  const int wm = wid >> 2, wn = wid & 3;
  const int g = lane >> 4, c = lane & 15;
  #pragma unroll
  for (int m = 0; m < 4; ++m)
    #pragma unroll
    for (int n = 0; n < 2; ++n)
      #pragma unroll
      for (int r = 0; r < 4; ++r) {
        int row = bx * 128 + wm * 64 + m * 16 + g * 4 + r;
        int col = by * 128 + wn * 32 + n * 16 + c;
        out[(size_t)row * C_ + col] = acc[m][n][r] + bp[col];
      }
}

extern "C" void kernel_launch(void* const* d_in, const int* in_sizes, int n_in,
                              void* d_out, int out_size, void* d_ws, size_t ws_size,
                              hipStream_t stream)
{
  const float* X  = (const float*)d_in[0];
  const float* Wq = (const float*)d_in[1];
  const float* Wk = (const float*)d_in[2];
  const float* Wv = (const float*)d_in[3];
  const float* Wp = (const float*)d_in[4];
  const float* bp = (const float*)d_in[5];
  float* out = (float*)d_out;

  char* ws = (char*)d_ws;
  bf16_t* Xb   = (bf16_t*)(ws);                       // 8 MB  [B*T][C]
  bf16_t* Wqb  = (bf16_t*)(ws + ((size_t)8  << 20));  // 2 MB  (Wq|Wk|Wv contiguous = Wqkv [3072][1024])
  bf16_t* Wkb  = (bf16_t*)(ws + ((size_t)10 << 20));  // 2 MB
  bf16_t* Wvb  = (bf16_t*)(ws + ((size_t)12 << 20));  // 2 MB
  bf16_t* Wpb  = (bf16_t*)(ws + ((size_t)14 << 20));  // 2 MB
  bf16_t* qo   = (bf16_t*)(ws + ((size_t)16 << 20));  // 8 MB  [B,H,T,D] (pre-scaled, exp2 domain)
  bf16_t* ko   = (bf16_t*)(ws + ((size_t)24 << 20));  // 8 MB  [B,H,T,D]
  bf16_t* vto  = (bf16_t*)(ws + ((size_t)32 << 20));  // 8 MB  [B,H,D,T]
  bf16_t* attb = (bf16_t*)(ws + ((size_t)40 << 20));  // 8 MB  [B,T,H*D]

  cast_all<<<8192, 256, 0, stream>>>(X, Wq, Wk, Wv, Wp, Xb, Wqb, Wkb, Wvb, Wpb);
  gemm_qkv<<<dim3(16, 12), 512, 0, stream>>>(Xb, Wqb, qo, ko, vto);
  attn_fwd<<<1024, 256, 0, stream>>>(qo, ko, vto, attb);
  gemm_proj<<<dim3(32, 8), 512, 0, stream>>>(attb, Wpb, bp, out);
}

// Round 10
// 91.598 us; speedup vs baseline: 1.0199x; 1.0199x over previous
//
#include <hip/hip_runtime.h>
#include <hip/hip_bf16.h>

typedef __bf16 bf16_t;
typedef __bf16 bf16x8 __attribute__((ext_vector_type(8)));
typedef __bf16 bf16x4 __attribute__((ext_vector_type(4)));
typedef float  f32x4  __attribute__((ext_vector_type(4)));
typedef unsigned int u32x4 __attribute__((ext_vector_type(4)));

#define MFMA16(a,b,c) __builtin_amdgcn_mfma_f32_16x16x32_bf16(a,b,c,0,0,0)

constexpr int B_ = 2, T_ = 2048, H_ = 16, D_ = 64, C_ = 1024;
constexpr int GK = C_;          // GEMM K dim (1024)

// async global->LDS, 16B per lane. LDS dest: wave-uniform base + lane*16.
typedef const __attribute__((address_space(1))) unsigned char ga_t;
typedef __attribute__((address_space(3))) unsigned char la_t;
__device__ __forceinline__ void gld16(const void* g, void* l) {
  __builtin_amdgcn_global_load_lds((ga_t*)g, (la_t*)l, 16, 0, 0);
}

// ---------------- cast fp32 -> bf16 (X, Wq, Wk, Wv, Wp) ----------------
__global__ __launch_bounds__(256) void cast_all(
    const float* __restrict__ X,  const float* __restrict__ Wq,
    const float* __restrict__ Wk, const float* __restrict__ Wv,
    const float* __restrict__ Wp,
    bf16_t* __restrict__ Xb,  bf16_t* __restrict__ Wqb, bf16_t* __restrict__ Wkb,
    bf16_t* __restrict__ Wvb, bf16_t* __restrict__ Wpb)
{
  int i = blockIdx.x * 256 + threadIdx.x;   // each thread converts 4 floats
  const float* src; bf16_t* dst; int off;
  if      (i < 1048576) { src = X;  dst = Xb;  off = i; }
  else if (i < 1310720) { src = Wq; dst = Wqb; off = i - 1048576; }
  else if (i < 1572864) { src = Wk; dst = Wkb; off = i - 1310720; }
  else if (i < 1835008) { src = Wv; dst = Wvb; off = i - 1572864; }
  else                  { src = Wp; dst = Wpb; off = i - 1835008; }
  float4 v = *reinterpret_cast<const float4*>(src + (size_t)off * 4);
  bf16x4 o;
  o[0] = (bf16_t)v.x; o[1] = (bf16_t)v.y; o[2] = (bf16_t)v.z; o[3] = (bf16_t)v.w;
  *reinterpret_cast<bf16x4*>(dst + (size_t)off * 4) = o;
}

// =============================================================================
// Shared 128x128 BK=64 counted-vmcnt GEMM core (kept for gemm_proj).
// =============================================================================
__device__ __forceinline__ void gemm128_core(
    const bf16_t* __restrict__ A, const bf16_t* __restrict__ Bw,
    bf16_t* sA, bf16_t* sB, f32x4 (&acc)[4][2], int bx, int by)
{
  const int tid = threadIdx.x, lane = tid & 63, wid = tid >> 6;
  const int wm = wid >> 2, wn = wid & 3;
  const int g = lane >> 4, c = lane & 15, rk = c & 7;
  const int srow = tid >> 3;                    // 0..63 rows per 64-row slab
  const int sg   = (tid & 7) ^ (srow & 7);      // pre-swizzled source granule
  const bf16_t* asrc = A  + (size_t)(bx * 128 + srow) * GK + sg * 8;
  const bf16_t* bsrc = Bw + (size_t)(by * 128 + srow) * GK + sg * 8;

  #define STGP(buf, kt)                                                       \
    { char* da = (char*)sA + (buf) * 16384;                                   \
      char* db = (char*)sB + (buf) * 16384;                                   \
      _Pragma("unroll")                                                       \
      for (int it = 0; it < 2; ++it) {                                        \
        gld16(asrc + (size_t)it * 65536 + (kt) * 64, da + (it * 512 + tid) * 16); \
        gld16(bsrc + (size_t)it * 65536 + (kt) * 64, db + (it * 512 + tid) * 16); \
      } }

  #define ITERP(t, buf)                                                       \
    {                                                                         \
      if ((t) < 15) asm volatile("s_waitcnt vmcnt(4)");                       \
      else          asm volatile("s_waitcnt vmcnt(0)");                       \
      __builtin_amdgcn_s_barrier();                                           \
      __builtin_amdgcn_sched_barrier(0);                                      \
      const char* ca = (const char*)sA + (buf) * 16384;                       \
      const char* cb = (const char*)sB + (buf) * 16384;                       \
      bf16x8 af[4][2], bfr[2][2];                                             \
      _Pragma("unroll")                                                       \
      for (int mi = 0; mi < 4; ++mi)                                          \
        _Pragma("unroll")                                                     \
        for (int ks = 0; ks < 2; ++ks)                                        \
          af[mi][ks] = *reinterpret_cast<const bf16x8*>(                      \
              ca + (wm * 64 + mi * 16 + c) * 128 + (((ks * 4 + g) ^ rk) * 16)); \
      _Pragma("unroll")                                                       \
      for (int ni = 0; ni < 2; ++ni)                                          \
        _Pragma("unroll")                                                     \
        for (int ks = 0; ks < 2; ++ks)                                        \
          bfr[ni][ks] = *reinterpret_cast<const bf16x8*>(                     \
              cb + (wn * 32 + ni * 16 + c) * 128 + (((ks * 4 + g) ^ rk) * 16)); \
      asm volatile("s_waitcnt lgkmcnt(0)");                                   \
      __builtin_amdgcn_sched_barrier(0);                                      \
      __builtin_amdgcn_s_barrier();                                           \
      __builtin_amdgcn_sched_barrier(0);                                      \
      if ((t) + 2 < 16) STGP(buf, (t) + 2);                                   \
      __builtin_amdgcn_s_setprio(1);                                          \
      _Pragma("unroll")                                                       \
      for (int ks = 0; ks < 2; ++ks)                                          \
        _Pragma("unroll")                                                     \
        for (int mi = 0; mi < 4; ++mi)                                        \
          _Pragma("unroll")                                                   \
          for (int ni = 0; ni < 2; ++ni)                                      \
            acc[mi][ni] = MFMA16(af[mi][ks], bfr[ni][ks], acc[mi][ni]);       \
      __builtin_amdgcn_s_setprio(0);                                          \
    }

  STGP(0, 0);                                   // prologue: 2 tiles in flight
  STGP(1, 1);
  #pragma unroll 1
  for (int t0 = 0; t0 < 16; t0 += 2) {
    ITERP(t0, 0);
    ITERP(t0 + 1, 1);
  }
  #undef ITERP
  #undef STGP
}

// ---------------- fused QKV projection: C[4096,3072] = Xb @ Wqkv^T -----------
// 128x192 tile, BK=64, 8 waves (2M x 4N), wave-tile 64x48 -> acc[4][3].
// Grid 32x16 = 512 blocks = EXACTLY one co-resident round (2 blk/CU x 256 CU)
// — R9 post-mortem: the 768-block config lost 25% to the scheduling tail
// (639 TF = 852 x 0.75). LDS 80KB -> 2 blk/CU. STG = 5 gld16/thread ->
// steady-state vmcnt(5). Same verified ITERP skeleton otherwise.
__global__ __launch_bounds__(512, 2) void gemm_qkv(
    const bf16_t* __restrict__ Xb, const bf16_t* __restrict__ Wqkv,
    bf16_t* __restrict__ qo, bf16_t* __restrict__ ko, bf16_t* __restrict__ vto)
{
  __shared__ bf16_t sA[2][128 * 64];            // 32 KB
  __shared__ bf16_t sB[2][192 * 64];            // 48 KB  (80 KB total)
  const int tid = threadIdx.x, lane = tid & 63, wid = tid >> 6;
  const int wm = wid >> 2, wn = wid & 3;
  const int g = lane >> 4, c = lane & 15, rk = c & 7;
  const int bx = blockIdx.x, by = blockIdx.y;
  const int srow = tid >> 3;                    // 0..63 rows per 64-row slab
  const int sg   = (tid & 7) ^ (srow & 7);      // pre-swizzled source granule
  const bf16_t* asrc = Xb   + (size_t)(bx * 128 + srow) * GK + sg * 8;
  const bf16_t* bsrc = Wqkv + (size_t)(by * 192 + srow) * GK + sg * 8;
  f32x4 acc[4][3] = {};

  // stage K-tile kt: 2 A-slabs + 3 B-slabs, 5 gld16/thread
  #define STGQ(buf, kt)                                                       \
    { char* da = (char*)sA + (buf) * 16384;                                   \
      char* db = (char*)sB + (buf) * 24576;                                   \
      _Pragma("unroll")                                                       \
      for (int it = 0; it < 2; ++it)                                          \
        gld16(asrc + (size_t)it * 65536 + (kt) * 64, da + (it * 512 + tid) * 16); \
      _Pragma("unroll")                                                       \
      for (int it = 0; it < 3; ++it)                                          \
        gld16(bsrc + (size_t)it * 65536 + (kt) * 64, db + (it * 512 + tid) * 16); \
    }

  #define ITERQ(t, buf)                                                       \
    {                                                                         \
      if ((t) < 15) asm volatile("s_waitcnt vmcnt(5)");                       \
      else          asm volatile("s_waitcnt vmcnt(0)");                       \
      __builtin_amdgcn_s_barrier();                                           \
      __builtin_amdgcn_sched_barrier(0);                                      \
      const char* ca = (const char*)sA + (buf) * 16384;                       \
      const char* cb = (const char*)sB + (buf) * 24576;                       \
      bf16x8 af[4][2], bfr[3][2];                                             \
      _Pragma("unroll")                                                       \
      for (int mi = 0; mi < 4; ++mi)                                          \
        _Pragma("unroll")                                                     \
        for (int ks = 0; ks < 2; ++ks)                                        \
          af[mi][ks] = *reinterpret_cast<const bf16x8*>(                      \
              ca + (wm * 64 + mi * 16 + c) * 128 + (((ks * 4 + g) ^ rk) * 16)); \
      _Pragma("unroll")                                                       \
      for (int ni = 0; ni < 3; ++ni)                                          \
        _Pragma("unroll")                                                     \
        for (int ks = 0; ks < 2; ++ks)                                        \
          bfr[ni][ks] = *reinterpret_cast<const bf16x8*>(                     \
              cb + (wn * 48 + ni * 16 + c) * 128 + (((ks * 4 + g) ^ rk) * 16)); \
      asm volatile("s_waitcnt lgkmcnt(0)");                                   \
      __builtin_amdgcn_sched_barrier(0);                                      \
      __builtin_amdgcn_s_barrier();                                           \
      __builtin_amdgcn_sched_barrier(0);                                      \
      if ((t) + 2 < 16) STGQ(buf, (t) + 2);                                   \
      __builtin_amdgcn_s_setprio(1);                                          \
      _Pragma("unroll")                                                       \
      for (int ks = 0; ks < 2; ++ks)                                          \
        _Pragma("unroll")                                                     \
        for (int mi = 0; mi < 4; ++mi)                                        \
          _Pragma("unroll")                                                   \
          for (int ni = 0; ni < 3; ++ni)                                      \
            acc[mi][ni] = MFMA16(af[mi][ks], bfr[ni][ks], acc[mi][ni]);       \
      __builtin_amdgcn_s_setprio(0);                                          \
    }

  STGQ(0, 0);                                   // prologue: 2 tiles in flight
  STGQ(1, 1);
  #pragma unroll 1
  for (int t0 = 0; t0 < 16; t0 += 2) {
    ITERQ(t0, 0);
    ITERQ(t0 + 1, 1);
  }
  #undef ITERQ
  #undef STGQ

  // epilogue: scatter to q / k / v^T. mode uniform per (wn, ni) across lanes
  // (16-col groups never straddle the 1024-col q/k/v boundary).
  const float qscale = 0.04508422002778f;       // log2(e) * 1024^-0.5
  #pragma unroll
  for (int ni = 0; ni < 3; ++ni) {
    int col  = by * 192 + wn * 48 + ni * 16 + c;
    int mode = col >> 10;
    int cm   = col & 1023;
    int h = cm >> 6, d = cm & 63;
    #pragma unroll
    for (int mi = 0; mi < 4; ++mi) {
      int row0 = bx * 128 + wm * 64 + mi * 16 + g * 4;
      int b = row0 >> 11, tt0 = row0 & 2047;
      if (mode == 2) {                          // v: [b,h,d,t] -> t contiguous
        bf16x4 wv;
        #pragma unroll
        for (int r = 0; r < 4; ++r) wv[r] = (bf16_t)acc[mi][ni][r];
        *reinterpret_cast<bf16x4*>(
            &vto[((size_t)(b * H_ + h) * D_ + d) * T_ + tt0]) = wv;
      } else {
        bf16_t* dst = (mode == 0) ? qo : ko;
        float   sc  = (mode == 0) ? qscale : 1.0f;
        #pragma unroll
        for (int r = 0; r < 4; ++r)
          dst[((size_t)(b * H_ + h) * T_ + (tt0 + r)) * D_ + d] =
              (bf16_t)(acc[mi][ni][r] * sc);
      }
    }
  }
}

// ---------------- flash attention (causal) -----------------------------------
// v4: 4-wave blocks, counted-vmcnt K/V pipeline, fixed-m softmax (m=8 folded
// into QK C-in; exp2 domain; 2^-8 cancels in O=PV/l), in-register P^T->B-frag
// via v_cvt_pk_bf16_f32 + permlane swaps (no sP LDS).
__global__ __launch_bounds__(256, 4) void attn_fwd(
    const bf16_t* __restrict__ q, const bf16_t* __restrict__ k,
    const bf16_t* __restrict__ vt, bf16_t* __restrict__ att)
{
  __shared__ bf16_t sK[2][64 * 64], sV[2][64 * 64];   // 16KB + 16KB
  const int tid = threadIdx.x, lane = tid & 63, w = tid >> 6;
  const int g = lane >> 4, c = lane & 15;
  const int bid = blockIdx.x;
  const int qt = 31 - (bid >> 5);                     // longest blocks first
  const int bh = bid & 31;
  const bf16_t* qb = q  + (size_t)bh * T_ * D_;
  const bf16_t* kb = k  + (size_t)bh * T_ * D_;
  const bf16_t* vb = vt + (size_t)bh * D_ * T_;       // vt[d][t]

  // Q fragments straight from global (read once)
  bf16x8 qa[2];
  #pragma unroll
  for (int ks = 0; ks < 2; ++ks)
    qa[ks] = *reinterpret_cast<const bf16x8*>(
        qb + (size_t)(qt * 64 + w * 16 + c) * D_ + ks * 32 + g * 8);

  // stage tile kt into buffer buf: 2 K-loads + 2 V-loads per thread (4 gld16)
  const int srow = tid >> 3, sgr0 = tid & 7;
  #define STAGE(buf, kt)                                                        \
    {                                                                           \
      char* kdst = (char*)sK + (size_t)(buf) * 8192;                            \
      char* vdst = (char*)sV + (size_t)(buf) * 8192;                            \
      _Pragma("unroll")                                                         \
      for (int it = 0; it < 2; ++it) {                                          \
        int idx = it * 256 + tid;                                               \
        int row = it * 32 + srow;                                               \
        int sg  = sgr0 ^ (row & 7);                                             \
        gld16(kb + (size_t)((kt) * 64 + row) * D_ + sg * 8, kdst + idx * 16);   \
        gld16(vb + (size_t)row * T_ + (kt) * 64 + sg * 8,   vdst + idx * 16);   \
      }                                                                         \
    }

  STAGE(0, 0);                                        // prologue: 2 in flight
  if (qt >= 1) STAGE(1, 1);

  float l_r = 0.f;                                    // per-lane l (q = c)
  f32x4 acc_t[4] = {};                                // O^T frags [d-block]
  const int rowK = c & 7;                             // swizzle key per lane

  #pragma unroll 1
  for (int kt = 0; kt <= qt; ++kt) {
    const int cur = kt & 1;
    if (kt < qt) asm volatile("s_waitcnt vmcnt(4)");
    else         asm volatile("s_waitcnt vmcnt(0)");
    __builtin_amdgcn_s_barrier();
    __builtin_amdgcn_sched_barrier(0);

    const char* kc = (char*)sK + (size_t)cur * 8192;
    const char* vc = (char*)sV + (size_t)cur * 8192;
    bf16x8 kf[2][4], vf[2][4];
    #pragma unroll
    for (int ks = 0; ks < 2; ++ks)
      #pragma unroll
      for (int f = 0; f < 4; ++f) {
        int rb = (f * 16 + c) * 128;
        int gsw = ((ks * 4 + g) ^ rowK) * 16;
        kf[ks][f] = *reinterpret_cast<const bf16x8*>(kc + rb + gsw);
        vf[ks][f] = *reinterpret_cast<const bf16x8*>(vc + rb + gsw);
      }
    asm volatile("s_waitcnt lgkmcnt(0)");             // my reads of buf done
    __builtin_amdgcn_sched_barrier(0);
    __builtin_amdgcn_s_barrier();                     // all waves' reads done
    __builtin_amdgcn_sched_barrier(0);
    if (kt + 2 <= qt) STAGE(cur, kt + 2);             // refill freed buffer

    // S^T - 8 = K Q^T + (-8): fixed-m softmax, m=8 folded into C-in
    f32x4 s[4];
    #pragma unroll
    for (int fj = 0; fj < 4; ++fj) {
      s[fj][0] = -8.f; s[fj][1] = -8.f; s[fj][2] = -8.f; s[fj][3] = -8.f;
    }
    __builtin_amdgcn_s_setprio(1);
    #pragma unroll
    for (int fj = 0; fj < 4; ++fj)
      #pragma unroll
      for (int ks = 0; ks < 2; ++ks)
        s[fj] = MFMA16(kf[ks][fj], qa[ks], s[fj]);
    __builtin_amdgcn_s_setprio(0);

    if (kt == qt) {                                   // causal mask on diagonal
      #pragma unroll
      for (int fj = 0; fj < 4; ++fj)
        #pragma unroll
        for (int r = 0; r < 4; ++r)
          if (fj * 16 + g * 4 + r > w * 16 + c) s[fj][r] = -1e30f;
    }

    // P = exp2(s); pack to bf16 pairs; tree-summed l (1 dependent add)
    unsigned pk[4][2];
    float ls[4];
    #pragma unroll
    for (int fj = 0; fj < 4; ++fj) {
      float pe0 = __builtin_amdgcn_exp2f(s[fj][0]);
      float pe1 = __builtin_amdgcn_exp2f(s[fj][1]);
      float pe2 = __builtin_amdgcn_exp2f(s[fj][2]);
      float pe3 = __builtin_amdgcn_exp2f(s[fj][3]);
      ls[fj] = (pe0 + pe1) + (pe2 + pe3);
      asm("v_cvt_pk_bf16_f32 %0, %1, %2" : "=v"(pk[fj][0]) : "v"(pe0), "v"(pe1));
      asm("v_cvt_pk_bf16_f32 %0, %1, %2" : "=v"(pk[fj][1]) : "v"(pe2), "v"(pe3));
    }
    l_r += (ls[0] + ls[1]) + (ls[2] + ls[3]);

    // in-register P^T -> B-frag redistribution (replaces sP LDS round-trip)
    bf16x8 pf[2];
    #pragma unroll
    for (int ks = 0; ks < 2; ++ks) {
      unsigned x0 = pk[2 * ks][0], y0 = pk[2 * ks + 1][0];
      unsigned x1 = pk[2 * ks][1], y1 = pk[2 * ks + 1][1];
      asm("v_permlane32_swap_b32 %0, %1" : "+v"(x0), "+v"(y0));
      asm("v_permlane32_swap_b32 %0, %1" : "+v"(x1), "+v"(y1));
      asm("v_permlane16_swap_b32 %0, %1" : "+v"(x0), "+v"(y0));
      asm("v_permlane16_swap_b32 %0, %1" : "+v"(x1), "+v"(y1));
      u32x4 t; t[0] = x0; t[1] = x1; t[2] = y0; t[3] = y1;
      pf[ks] = __builtin_bit_cast(bf16x8, t);
    }

    // O^T += V^T P^T
    __builtin_amdgcn_s_setprio(1);
    #pragma unroll
    for (int fd = 0; fd < 4; ++fd)
      #pragma unroll
      for (int ks = 0; ks < 2; ++ks)
        acc_t[fd] = MFMA16(vf[ks][fd], pf[ks], acc_t[fd]);
    __builtin_amdgcn_s_setprio(0);
  }

  // deferred l reduce across the 4 g-groups, then write O
  l_r += __shfl_xor(l_r, 16);
  l_r += __shfl_xor(l_r, 32);
  float inv = 1.0f / l_r;
  const int b = bh >> 4, h = bh & 15;
  const int t = qt * 64 + w * 16 + c;
  #pragma unroll
  for (int fd = 0; fd < 4; ++fd) {
    bf16x4 wv;
    #pragma unroll
    for (int r = 0; r < 4; ++r) wv[r] = (bf16_t)(acc_t[fd][r] * inv);
    int d = fd * 16 + g * 4;
    *reinterpret_cast<bf16x4*>(&att[((size_t)(b * T_ + t) * H_ + h) * D_ + d]) = wv;
  }
  #undef STAGE
}

// ---------------- output projection: out = att @ Wp^T + bp (fp32 out) --------
__global__ __launch_bounds__(512, 2) void gemm_proj(
    const bf16_t* __restrict__ attb, const bf16_t* __restrict__ Wpb,
    const float* __restrict__ bp, float* __restrict__ out)
{
  __shared__ bf16_t sA[2][128 * 64];            // 32 KB
  __shared__ bf16_t sB[2][128 * 64];            // 32 KB
  f32x4 acc[4][2] = {};
  const int bx = blockIdx.x, by = blockIdx.y;
  gemm128_core(attb, Wpb, &sA[0][0], &sB[0][0], acc, bx, by);

  const int tid = threadIdx.x, lane = tid & 63, wid = tid >> 6;
  const int wm = wid >> 2, wn = wid & 3;
  const int g = lane >> 4, c = lane & 15;
  #pragma unroll
  for (int m = 0; m < 4; ++m)
    #pragma unroll
    for (int n = 0; n < 2; ++n)
      #pragma unroll
      for (int r = 0; r < 4; ++r) {
        int row = bx * 128 + wm * 64 + m * 16 + g * 4 + r;
        int col = by * 128 + wn * 32 + n * 16 + c;
        out[(size_t)row * C_ + col] = acc[m][n][r] + bp[col];
      }
}

extern "C" void kernel_launch(void* const* d_in, const int* in_sizes, int n_in,
                              void* d_out, int out_size, void* d_ws, size_t ws_size,
                              hipStream_t stream)
{
  const float* X  = (const float*)d_in[0];
  const float* Wq = (const float*)d_in[1];
  const float* Wk = (const float*)d_in[2];
  const float* Wv = (const float*)d_in[3];
  const float* Wp = (const float*)d_in[4];
  const float* bp = (const float*)d_in[5];
  float* out = (float*)d_out;

  char* ws = (char*)d_ws;
  bf16_t* Xb   = (bf16_t*)(ws);                       // 8 MB  [B*T][C]
  bf16_t* Wqb  = (bf16_t*)(ws + ((size_t)8  << 20));  // 2 MB  (Wq|Wk|Wv contiguous = Wqkv [3072][1024])
  bf16_t* Wkb  = (bf16_t*)(ws + ((size_t)10 << 20));  // 2 MB
  bf16_t* Wvb  = (bf16_t*)(ws + ((size_t)12 << 20));  // 2 MB
  bf16_t* Wpb  = (bf16_t*)(ws + ((size_t)14 << 20));  // 2 MB
  bf16_t* qo   = (bf16_t*)(ws + ((size_t)16 << 20));  // 8 MB  [B,H,T,D] (pre-scaled, exp2 domain)
  bf16_t* ko   = (bf16_t*)(ws + ((size_t)24 << 20));  // 8 MB  [B,H,T,D]
  bf16_t* vto  = (bf16_t*)(ws + ((size_t)32 << 20));  // 8 MB  [B,H,D,T]
  bf16_t* attb = (bf16_t*)(ws + ((size_t)40 << 20));  // 8 MB  [B,T,H*D]

  cast_all<<<8192, 256, 0, stream>>>(X, Wq, Wk, Wv, Wp, Xb, Wqb, Wkb, Wvb, Wpb);
  gemm_qkv<<<dim3(32, 16), 512, 0, stream>>>(Xb, Wqb, qo, ko, vto);
  attn_fwd<<<1024, 256, 0, stream>>>(qo, ko, vto, attb);
  gemm_proj<<<dim3(32, 8), 512, 0, stream>>>(attb, Wpb, bp, out);
}

// Round 11
// 87.448 us; speedup vs baseline: 1.0683x; 1.0475x over previous
//
#include <hip/hip_runtime.h>
#include <hip/hip_bf16.h>

typedef __bf16 bf16_t;
typedef __bf16 bf16x8 __attribute__((ext_vector_type(8)));
typedef __bf16 bf16x4 __attribute__((ext_vector_type(4)));
typedef float  f32x4  __attribute__((ext_vector_type(4)));
typedef unsigned int u32x4 __attribute__((ext_vector_type(4)));

#define MFMA16(a,b,c) __builtin_amdgcn_mfma_f32_16x16x32_bf16(a,b,c,0,0,0)

constexpr int B_ = 2, T_ = 2048, H_ = 16, D_ = 64, C_ = 1024;
constexpr int GK = C_;          // GEMM K dim (1024)

// async global->LDS, 16B per lane. LDS dest: wave-uniform base + lane*16.
typedef const __attribute__((address_space(1))) unsigned char ga_t;
typedef __attribute__((address_space(3))) unsigned char la_t;
__device__ __forceinline__ void gld16(const void* g, void* l) {
  __builtin_amdgcn_global_load_lds((ga_t*)g, (la_t*)l, 16, 0, 0);
}

// ---------------- cast fp32 -> bf16 (X, Wq, Wk, Wv, Wp) ----------------
__global__ __launch_bounds__(256) void cast_all(
    const float* __restrict__ X,  const float* __restrict__ Wq,
    const float* __restrict__ Wk, const float* __restrict__ Wv,
    const float* __restrict__ Wp,
    bf16_t* __restrict__ Xb,  bf16_t* __restrict__ Wqb, bf16_t* __restrict__ Wkb,
    bf16_t* __restrict__ Wvb, bf16_t* __restrict__ Wpb)
{
  int i = blockIdx.x * 256 + threadIdx.x;   // each thread converts 4 floats
  const float* src; bf16_t* dst; int off;
  if      (i < 1048576) { src = X;  dst = Xb;  off = i; }
  else if (i < 1310720) { src = Wq; dst = Wqb; off = i - 1048576; }
  else if (i < 1572864) { src = Wk; dst = Wkb; off = i - 1310720; }
  else if (i < 1835008) { src = Wv; dst = Wvb; off = i - 1572864; }
  else                  { src = Wp; dst = Wpb; off = i - 1835008; }
  float4 v = *reinterpret_cast<const float4*>(src + (size_t)off * 4);
  bf16x4 o;
  o[0] = (bf16_t)v.x; o[1] = (bf16_t)v.y; o[2] = (bf16_t)v.z; o[3] = (bf16_t)v.w;
  *reinterpret_cast<bf16x4*>(dst + (size_t)off * 4) = o;
}

// =============================================================================
// Shared 128x128 BK=64 counted-vmcnt GEMM core — UNPINNED (R10 post-mortem):
// all sched_barrier(0) pins removed (m141: order-pinning defeats the
// compiler's fine-grained lgkmcnt interleave, 874->510 TF). The two required
// memory orderings are kept via "memory" clobbers on the waitcnt asms:
//  (a) ds_reads can't hoist above the buffer-ready barrier,
//  (b) ds_reads complete before the buffer-free barrier (STAGE overwrites).
// Register-only MFMAs are free to interleave across the whole region.
// =============================================================================
__device__ __forceinline__ void gemm128_core(
    const bf16_t* __restrict__ A, const bf16_t* __restrict__ Bw,
    bf16_t* sA, bf16_t* sB, f32x4 (&acc)[4][2], int bx, int by)
{
  const int tid = threadIdx.x, lane = tid & 63, wid = tid >> 6;
  const int wm = wid >> 2, wn = wid & 3;
  const int g = lane >> 4, c = lane & 15, rk = c & 7;
  const int srow = tid >> 3;                    // 0..63 rows per 64-row slab
  const int sg   = (tid & 7) ^ (srow & 7);      // pre-swizzled source granule
  const bf16_t* asrc = A  + (size_t)(bx * 128 + srow) * GK + sg * 8;
  const bf16_t* bsrc = Bw + (size_t)(by * 128 + srow) * GK + sg * 8;

  #define STGP(buf, kt)                                                       \
    { char* da = (char*)sA + (buf) * 16384;                                   \
      char* db = (char*)sB + (buf) * 16384;                                   \
      _Pragma("unroll")                                                       \
      for (int it = 0; it < 2; ++it) {                                        \
        gld16(asrc + (size_t)it * 65536 + (kt) * 64, da + (it * 512 + tid) * 16); \
        gld16(bsrc + (size_t)it * 65536 + (kt) * 64, db + (it * 512 + tid) * 16); \
      } }

  #define ITERP(t, buf)                                                       \
    {                                                                         \
      if ((t) < 15) asm volatile("s_waitcnt vmcnt(4)" ::: "memory");          \
      else          asm volatile("s_waitcnt vmcnt(0)" ::: "memory");          \
      __builtin_amdgcn_s_barrier();             /* buf[cur] ready */          \
      const char* ca = (const char*)sA + (buf) * 16384;                       \
      const char* cb = (const char*)sB + (buf) * 16384;                       \
      bf16x8 af[4][2], bfr[2][2];                                             \
      _Pragma("unroll")                                                       \
      for (int mi = 0; mi < 4; ++mi)                                          \
        _Pragma("unroll")                                                     \
        for (int ks = 0; ks < 2; ++ks)                                        \
          af[mi][ks] = *reinterpret_cast<const bf16x8*>(                      \
              ca + (wm * 64 + mi * 16 + c) * 128 + (((ks * 4 + g) ^ rk) * 16)); \
      _Pragma("unroll")                                                       \
      for (int ni = 0; ni < 2; ++ni)                                          \
        _Pragma("unroll")                                                     \
        for (int ks = 0; ks < 2; ++ks)                                        \
          bfr[ni][ks] = *reinterpret_cast<const bf16x8*>(                     \
              cb + (wn * 32 + ni * 16 + c) * 128 + (((ks * 4 + g) ^ rk) * 16)); \
      asm volatile("s_waitcnt lgkmcnt(0)" ::: "memory"); /* my reads done */  \
      __builtin_amdgcn_s_barrier();             /* all reads done */          \
      if ((t) + 2 < 16) STGP(buf, (t) + 2);     /* refill freed buffer */     \
      __builtin_amdgcn_s_setprio(1);                                          \
      _Pragma("unroll")                                                       \
      for (int ks = 0; ks < 2; ++ks)                                          \
        _Pragma("unroll")                                                     \
        for (int mi = 0; mi < 4; ++mi)                                        \
          _Pragma("unroll")                                                   \
          for (int ni = 0; ni < 2; ++ni)                                      \
            acc[mi][ni] = MFMA16(af[mi][ks], bfr[ni][ks], acc[mi][ni]);       \
      __builtin_amdgcn_s_setprio(0);                                          \
    }

  STGP(0, 0);                                   // prologue: 2 tiles in flight
  STGP(1, 1);
  #pragma unroll 1
  for (int t0 = 0; t0 < 16; t0 += 2) {
    ITERP(t0, 0);
    ITERP(t0 + 1, 1);
  }
  #undef ITERP
  #undef STGP
}

// ---------------- fused QKV projection: C[4096,3072] = Xb @ Wqkv^T -----------
// 128x128 tile (R7 config — best measured), grid 32x24 = 768 blocks.
// mode = by>>3 is block-uniform (1024 cols per projection / 128-col tiles).
__global__ __launch_bounds__(512, 2) void gemm_qkv(
    const bf16_t* __restrict__ Xb, const bf16_t* __restrict__ Wqkv,
    bf16_t* __restrict__ qo, bf16_t* __restrict__ ko, bf16_t* __restrict__ vto)
{
  __shared__ bf16_t sA[2][128 * 64];            // 32 KB
  __shared__ bf16_t sB[2][128 * 64];            // 32 KB
  f32x4 acc[4][2] = {};
  const int bx = blockIdx.x, by = blockIdx.y;
  gemm128_core(Xb, Wqkv, &sA[0][0], &sB[0][0], acc, bx, by);

  const int tid = threadIdx.x, lane = tid & 63, wid = tid >> 6;
  const int wm = wid >> 2, wn = wid & 3;
  const int g = lane >> 4, c = lane & 15;
  const float qscale = 0.04508422002778f;       // log2(e) * 1024^-0.5
  const int mode = by >> 3;                     // 0=q, 1=k, 2=v (block-uniform)
  #pragma unroll
  for (int ni = 0; ni < 2; ++ni) {
    int col = by * 128 + wn * 32 + ni * 16 + c;
    int cm  = col & 1023;
    int h = cm >> 6, d = cm & 63;
    #pragma unroll
    for (int mi = 0; mi < 4; ++mi) {
      int row0 = bx * 128 + wm * 64 + mi * 16 + g * 4;
      int b = row0 >> 11, tt0 = row0 & 2047;
      if (mode == 2) {                          // v: [b,h,d,t] -> t contiguous
        bf16x4 wv;
        #pragma unroll
        for (int r = 0; r < 4; ++r) wv[r] = (bf16_t)acc[mi][ni][r];
        *reinterpret_cast<bf16x4*>(
            &vto[((size_t)(b * H_ + h) * D_ + d) * T_ + tt0]) = wv;
      } else {
        bf16_t* dst = (mode == 0) ? qo : ko;
        float   sc  = (mode == 0) ? qscale : 1.0f;
        #pragma unroll
        for (int r = 0; r < 4; ++r)
          dst[((size_t)(b * H_ + h) * T_ + (tt0 + r)) * D_ + d] =
              (bf16_t)(acc[mi][ni][r] * sc);
      }
    }
  }
}

// ---------------- flash attention (causal) -----------------------------------
// v4 core (best measured) with the same unpinning: sched_barrier(0) pins
// removed, "memory" clobbers on the two waitcnts. Fixed-m softmax (m=8 in
// QK C-in, exp2 domain, cancels in O=PV/l); in-register P^T->B-frag via
// cvt_pk + permlane swaps (no sP LDS).
__global__ __launch_bounds__(256, 4) void attn_fwd(
    const bf16_t* __restrict__ q, const bf16_t* __restrict__ k,
    const bf16_t* __restrict__ vt, bf16_t* __restrict__ att)
{
  __shared__ bf16_t sK[2][64 * 64], sV[2][64 * 64];   // 16KB + 16KB
  const int tid = threadIdx.x, lane = tid & 63, w = tid >> 6;
  const int g = lane >> 4, c = lane & 15;
  const int bid = blockIdx.x;
  const int qt = 31 - (bid >> 5);                     // longest blocks first
  const int bh = bid & 31;
  const bf16_t* qb = q  + (size_t)bh * T_ * D_;
  const bf16_t* kb = k  + (size_t)bh * T_ * D_;
  const bf16_t* vb = vt + (size_t)bh * D_ * T_;       // vt[d][t]

  // Q fragments straight from global (read once)
  bf16x8 qa[2];
  #pragma unroll
  for (int ks = 0; ks < 2; ++ks)
    qa[ks] = *reinterpret_cast<const bf16x8*>(
        qb + (size_t)(qt * 64 + w * 16 + c) * D_ + ks * 32 + g * 8);

  // stage tile kt into buffer buf: 2 K-loads + 2 V-loads per thread (4 gld16)
  const int srow = tid >> 3, sgr0 = tid & 7;
  #define STAGE(buf, kt)                                                        \
    {                                                                           \
      char* kdst = (char*)sK + (size_t)(buf) * 8192;                            \
      char* vdst = (char*)sV + (size_t)(buf) * 8192;                            \
      _Pragma("unroll")                                                         \
      for (int it = 0; it < 2; ++it) {                                          \
        int idx = it * 256 + tid;                                               \
        int row = it * 32 + srow;                                               \
        int sg  = sgr0 ^ (row & 7);                                             \
        gld16(kb + (size_t)((kt) * 64 + row) * D_ + sg * 8, kdst + idx * 16);   \
        gld16(vb + (size_t)row * T_ + (kt) * 64 + sg * 8,   vdst + idx * 16);   \
      }                                                                         \
    }

  STAGE(0, 0);                                        // prologue: 2 in flight
  if (qt >= 1) STAGE(1, 1);

  float l_r = 0.f;                                    // per-lane l (q = c)
  f32x4 acc_t[4] = {};                                // O^T frags [d-block]
  const int rowK = c & 7;                             // swizzle key per lane

  #pragma unroll 1
  for (int kt = 0; kt <= qt; ++kt) {
    const int cur = kt & 1;
    if (kt < qt) asm volatile("s_waitcnt vmcnt(4)" ::: "memory");
    else         asm volatile("s_waitcnt vmcnt(0)" ::: "memory");
    __builtin_amdgcn_s_barrier();                     // buf[cur] ready

    const char* kc = (char*)sK + (size_t)cur * 8192;
    const char* vc = (char*)sV + (size_t)cur * 8192;
    bf16x8 kf[2][4], vf[2][4];
    #pragma unroll
    for (int ks = 0; ks < 2; ++ks)
      #pragma unroll
      for (int f = 0; f < 4; ++f) {
        int rb = (f * 16 + c) * 128;
        int gsw = ((ks * 4 + g) ^ rowK) * 16;
        kf[ks][f] = *reinterpret_cast<const bf16x8*>(kc + rb + gsw);
        vf[ks][f] = *reinterpret_cast<const bf16x8*>(vc + rb + gsw);
      }
    asm volatile("s_waitcnt lgkmcnt(0)" ::: "memory"); // my reads of buf done
    __builtin_amdgcn_s_barrier();                     // all waves' reads done
    if (kt + 2 <= qt) STAGE(cur, kt + 2);             // refill freed buffer

    // S^T - 8 = K Q^T + (-8): fixed-m softmax, m=8 folded into C-in
    f32x4 s[4];
    #pragma unroll
    for (int fj = 0; fj < 4; ++fj) {
      s[fj][0] = -8.f; s[fj][1] = -8.f; s[fj][2] = -8.f; s[fj][3] = -8.f;
    }
    __builtin_amdgcn_s_setprio(1);
    #pragma unroll
    for (int fj = 0; fj < 4; ++fj)
      #pragma unroll
      for (int ks = 0; ks < 2; ++ks)
        s[fj] = MFMA16(kf[ks][fj], qa[ks], s[fj]);
    __builtin_amdgcn_s_setprio(0);

    if (kt == qt) {                                   // causal mask on diagonal
      #pragma unroll
      for (int fj = 0; fj < 4; ++fj)
        #pragma unroll
        for (int r = 0; r < 4; ++r)
          if (fj * 16 + g * 4 + r > w * 16 + c) s[fj][r] = -1e30f;
    }

    // P = exp2(s); pack to bf16 pairs; tree-summed l (1 dependent add)
    unsigned pk[4][2];
    float ls[4];
    #pragma unroll
    for (int fj = 0; fj < 4; ++fj) {
      float pe0 = __builtin_amdgcn_exp2f(s[fj][0]);
      float pe1 = __builtin_amdgcn_exp2f(s[fj][1]);
      float pe2 = __builtin_amdgcn_exp2f(s[fj][2]);
      float pe3 = __builtin_amdgcn_exp2f(s[fj][3]);
      ls[fj] = (pe0 + pe1) + (pe2 + pe3);
      asm("v_cvt_pk_bf16_f32 %0, %1, %2" : "=v"(pk[fj][0]) : "v"(pe0), "v"(pe1));
      asm("v_cvt_pk_bf16_f32 %0, %1, %2" : "=v"(pk[fj][1]) : "v"(pe2), "v"(pe3));
    }
    l_r += (ls[0] + ls[1]) + (ls[2] + ls[3]);

    // in-register P^T -> B-frag redistribution (replaces sP LDS round-trip)
    bf16x8 pf[2];
    #pragma unroll
    for (int ks = 0; ks < 2; ++ks) {
      unsigned x0 = pk[2 * ks][0], y0 = pk[2 * ks + 1][0];
      unsigned x1 = pk[2 * ks][1], y1 = pk[2 * ks + 1][1];
      asm("v_permlane32_swap_b32 %0, %1" : "+v"(x0), "+v"(y0));
      asm("v_permlane32_swap_b32 %0, %1" : "+v"(x1), "+v"(y1));
      asm("v_permlane16_swap_b32 %0, %1" : "+v"(x0), "+v"(y0));
      asm("v_permlane16_swap_b32 %0, %1" : "+v"(x1), "+v"(y1));
      u32x4 t; t[0] = x0; t[1] = x1; t[2] = y0; t[3] = y1;
      pf[ks] = __builtin_bit_cast(bf16x8, t);
    }

    // O^T += V^T P^T
    __builtin_amdgcn_s_setprio(1);
    #pragma unroll
    for (int fd = 0; fd < 4; ++fd)
      #pragma unroll
      for (int ks = 0; ks < 2; ++ks)
        acc_t[fd] = MFMA16(vf[ks][fd], pf[ks], acc_t[fd]);
    __builtin_amdgcn_s_setprio(0);
  }

  // deferred l reduce across the 4 g-groups, then write O
  l_r += __shfl_xor(l_r, 16);
  l_r += __shfl_xor(l_r, 32);
  float inv = 1.0f / l_r;
  const int b = bh >> 4, h = bh & 15;
  const int t = qt * 64 + w * 16 + c;
  #pragma unroll
  for (int fd = 0; fd < 4; ++fd) {
    bf16x4 wv;
    #pragma unroll
    for (int r = 0; r < 4; ++r) wv[r] = (bf16_t)(acc_t[fd][r] * inv);
    int d = fd * 16 + g * 4;
    *reinterpret_cast<bf16x4*>(&att[((size_t)(b * T_ + t) * H_ + h) * D_ + d]) = wv;
  }
  #undef STAGE
}

// ---------------- output projection: out = att @ Wp^T + bp (fp32 out) --------
__global__ __launch_bounds__(512, 2) void gemm_proj(
    const bf16_t* __restrict__ attb, const bf16_t* __restrict__ Wpb,
    const float* __restrict__ bp, float* __restrict__ out)
{
  __shared__ bf16_t sA[2][128 * 64];            // 32 KB
  __shared__ bf16_t sB[2][128 * 64];            // 32 KB
  f32x4 acc[4][2] = {};
  const int bx = blockIdx.x, by = blockIdx.y;
  gemm128_core(attb, Wpb, &sA[0][0], &sB[0][0], acc, bx, by);

  const int tid = threadIdx.x, lane = tid & 63, wid = tid >> 6;
  const int wm = wid >> 2, wn = wid & 3;
  const int g = lane >> 4, c = lane & 15;
  #pragma unroll
  for (int m = 0; m < 4; ++m)
    #pragma unroll
    for (int n = 0; n < 2; ++n)
      #pragma unroll
      for (int r = 0; r < 4; ++r) {
        int row = bx * 128 + wm * 64 + m * 16 + g * 4 + r;
        int col = by * 128 + wn * 32 + n * 16 + c;
        out[(size_t)row * C_ + col] = acc[m][n][r] + bp[col];
      }
}

extern "C" void kernel_launch(void* const* d_in, const int* in_sizes, int n_in,
                              void* d_out, int out_size, void* d_ws, size_t ws_size,
                              hipStream_t stream)
{
  const float* X  = (const float*)d_in[0];
  const float* Wq = (const float*)d_in[1];
  const float* Wk = (const float*)d_in[2];
  const float* Wv = (const float*)d_in[3];
  const float* Wp = (const float*)d_in[4];
  const float* bp = (const float*)d_in[5];
  float* out = (float*)d_out;

  char* ws = (char*)d_ws;
  bf16_t* Xb   = (bf16_t*)(ws);                       // 8 MB  [B*T][C]
  bf16_t* Wqb  = (bf16_t*)(ws + ((size_t)8  << 20));  // 2 MB  (Wq|Wk|Wv contiguous = Wqkv [3072][1024])
  bf16_t* Wkb  = (bf16_t*)(ws + ((size_t)10 << 20));  // 2 MB
  bf16_t* Wvb  = (bf16_t*)(ws + ((size_t)12 << 20));  // 2 MB
  bf16_t* Wpb  = (bf16_t*)(ws + ((size_t)14 << 20));  // 2 MB
  bf16_t* qo   = (bf16_t*)(ws + ((size_t)16 << 20));  // 8 MB  [B,H,T,D] (pre-scaled, exp2 domain)
  bf16_t* ko   = (bf16_t*)(ws + ((size_t)24 << 20));  // 8 MB  [B,H,T,D]
  bf16_t* vto  = (bf16_t*)(ws + ((size_t)32 << 20));  // 8 MB  [B,H,D,T]
  bf16_t* attb = (bf16_t*)(ws + ((size_t)40 << 20));  // 8 MB  [B,T,H*D]

  cast_all<<<8192, 256, 0, stream>>>(X, Wq, Wk, Wv, Wp, Xb, Wqb, Wkb, Wvb, Wpb);
  gemm_qkv<<<dim3(32, 24), 512, 0, stream>>>(Xb, Wqb, qo, ko, vto);
  attn_fwd<<<1024, 256, 0, stream>>>(qo, ko, vto, attb);
  gemm_proj<<<dim3(32, 8), 512, 0, stream>>>(attb, Wpb, bp, out);
}